// Round 1
// baseline (5503.470 us; speedup 1.0000x reference)
//
#include <hip/hip_runtime.h>
#include <hip/hip_bf16.h>

#define DIMSZ 2048
#define LSEQ 2048
#define NHEADS 16
#define NKVH 8
#define HDIM 128
#define HHALF 64
#define EPSV 1e-5f
#define LAMB 0.2f
#define SM_SCALE 0.125f

// ---------------- RMSNorm: one block per row ----------------
__global__ __launch_bounds__(256) void rmsnorm_kernel(const float* __restrict__ x,
                                                      const float* __restrict__ w,
                                                      float* __restrict__ out)
{
    int row = blockIdx.x;
    int t = threadIdx.x;
    const float* xr = x + (size_t)row * DIMSZ;
    float4 v0 = ((const float4*)xr)[t];
    float4 v1 = ((const float4*)xr)[t + 256];
    float s = v0.x*v0.x + v0.y*v0.y + v0.z*v0.z + v0.w*v0.w
            + v1.x*v1.x + v1.y*v1.y + v1.z*v1.z + v1.w*v1.w;
    #pragma unroll
    for (int m = 1; m < 64; m <<= 1) s += __shfl_xor(s, m, 64);
    __shared__ float red[4];
    int wid = t >> 6;
    if ((t & 63) == 0) red[wid] = s;
    __syncthreads();
    float tot = red[0] + red[1] + red[2] + red[3];
    float inv = rsqrtf(tot * (1.0f / DIMSZ) + EPSV);
    float4 w0 = ((const float4*)w)[t];
    float4 w1v = ((const float4*)w)[t + 256];
    float* orow = out + (size_t)row * DIMSZ;
    float4 r0, r1;
    r0.x = v0.x*inv*w0.x; r0.y = v0.y*inv*w0.y; r0.z = v0.z*inv*w0.z; r0.w = v0.w*inv*w0.w;
    r1.x = v1.x*inv*w1v.x; r1.y = v1.y*inv*w1v.y; r1.z = v1.z*inv*w1v.z; r1.w = v1.w*inv*w1v.w;
    ((float4*)orow)[t] = r0;
    ((float4*)orow)[t + 256] = r1;
}

// ---------------- RoPE (in-place, interleaved pairs) ----------------
__global__ __launch_bounds__(256) void rope_kernel(float* __restrict__ buf,
                                                   const float* __restrict__ cosT,
                                                   const float* __restrict__ sinT,
                                                   int log2nh)
{
    int idx = blockIdx.x * 256 + threadIdx.x;  // (l, head, j), j fastest
    int j = idx & 63;
    int hl = idx >> 6;
    int l = hl >> log2nh;
    float c = cosT[l * 64 + j];
    float s = sinT[l * 64 + j];
    float2 v = ((float2*)buf)[idx];
    float2 r;
    r.x = v.x * c - v.y * s;
    r.y = v.x * s + v.y * c;
    ((float2*)buf)[idx] = r;
}

// ---------------- fp32 GEMM: C[M,N] = A[M,K] * B[K,N] (+ epilogue) ----------------
// EPI 0: C = acc ; EPI 1: C = R + acc ; EPI 2: C = silu(R) * acc
template<int EPI>
__global__ __launch_bounds__(256) void gemm_f32(const float* __restrict__ A,
                                                const float* __restrict__ B,
                                                float* __restrict__ C,
                                                const float* __restrict__ R,
                                                int M, int N, int K)
{
    __shared__ float As[16][132];
    __shared__ float Bs[16][132];
    int t = threadIdx.x;
    int tx = t & 15, ty = t >> 4;
    int row0 = blockIdx.y * 128, col0 = blockIdx.x * 128;

    int mA = t >> 1;            // 0..127
    int kA = (t & 1) * 8;       // 0 or 8
    int kB = t >> 4;            // 0..15
    int nB = (t & 15) * 8;      // 0..120

    const float* Ap = A + (size_t)(row0 + mA) * K + kA;
    const float* Bp = B + (size_t)kB * N + col0 + nB;

    float acc[8][8];
    #pragma unroll
    for (int i = 0; i < 8; ++i)
        #pragma unroll
        for (int j = 0; j < 8; ++j) acc[i][j] = 0.0f;

    for (int k0 = 0; k0 < K; k0 += 16) {
        float4 a0 = *(const float4*)(Ap + k0);
        float4 a1 = *(const float4*)(Ap + k0 + 4);
        float4 b0 = *(const float4*)(Bp + (size_t)k0 * N);
        float4 b1 = *(const float4*)(Bp + (size_t)k0 * N + 4);
        __syncthreads();
        As[kA + 0][mA] = a0.x; As[kA + 1][mA] = a0.y; As[kA + 2][mA] = a0.z; As[kA + 3][mA] = a0.w;
        As[kA + 4][mA] = a1.x; As[kA + 5][mA] = a1.y; As[kA + 6][mA] = a1.z; As[kA + 7][mA] = a1.w;
        *(float4*)&Bs[kB][nB] = b0;
        *(float4*)&Bs[kB][nB + 4] = b1;
        __syncthreads();
        #pragma unroll
        for (int kk = 0; kk < 16; ++kk) {
            float4 xa0 = *(const float4*)&As[kk][ty * 8];
            float4 xa1 = *(const float4*)&As[kk][ty * 8 + 4];
            float4 yb0 = *(const float4*)&Bs[kk][tx * 8];
            float4 yb1 = *(const float4*)&Bs[kk][tx * 8 + 4];
            float av[8] = {xa0.x, xa0.y, xa0.z, xa0.w, xa1.x, xa1.y, xa1.z, xa1.w};
            float bv[8] = {yb0.x, yb0.y, yb0.z, yb0.w, yb1.x, yb1.y, yb1.z, yb1.w};
            #pragma unroll
            for (int i = 0; i < 8; ++i)
                #pragma unroll
                for (int j = 0; j < 8; ++j)
                    acc[i][j] += av[i] * bv[j];
        }
    }

    #pragma unroll
    for (int i = 0; i < 8; ++i) {
        size_t base = (size_t)(row0 + ty * 8 + i) * N + col0 + tx * 8;
        float ov[8];
        #pragma unroll
        for (int j = 0; j < 8; ++j) ov[j] = acc[i][j];
        if (EPI == 1) {
            #pragma unroll
            for (int j = 0; j < 8; ++j) ov[j] += R[base + j];
        } else if (EPI == 2) {
            #pragma unroll
            for (int j = 0; j < 8; ++j) {
                float uv = R[base + j];
                ov[j] = (uv / (1.0f + __expf(-uv))) * ov[j];
            }
        }
        float4 s0 = {ov[0], ov[1], ov[2], ov[3]};
        float4 s1v = {ov[4], ov[5], ov[6], ov[7]};
        *(float4*)&C[base] = s0;
        *(float4*)&C[base + 4] = s1v;
    }
}

// ---------------- Differential GQA flash attention ----------------
// grid (L/64, NH); block 256 = 16x16 threads
__global__ __launch_bounds__(256) void attn_kernel(const float* __restrict__ Q,
                                                   const float* __restrict__ K,
                                                   const float* __restrict__ V,
                                                   float* __restrict__ O)
{
    constexpr int BQ = 64, BT = 32;
    int qb = blockIdx.x, h = blockIdx.y;
    int kvh = h >> 1;
    int t = threadIdx.x;
    int tx = t & 15, ty = t >> 4;

    __shared__ float Qs[BQ][132];
    __shared__ float Ks[BT][136];
    __shared__ float Vs[BT][128];
    __shared__ float Ps[BQ][33];

    {   // load Q tile (64 rows x 128)
        int r = t >> 2;
        int c0 = (t & 3) * 4;
        const float* src = Q + (size_t)(qb * BQ + r) * (NHEADS * HDIM) + h * HDIM + c0;
        #pragma unroll
        for (int s = 0; s < 8; ++s) {
            float4 vq = *(const float4*)(src + s * 16);
            *(float4*)&Qs[r][c0 + s * 16] = vq;
        }
    }

    float m1[4], l1[4], m2[4], l2[4];
    float o1[4][8], o2[4][8];
    #pragma unroll
    for (int i = 0; i < 4; ++i) {
        m1[i] = -1e30f; m2[i] = -1e30f; l1[i] = 0.0f; l2[i] = 0.0f;
        #pragma unroll
        for (int d = 0; d < 8; ++d) { o1[i][d] = 0.0f; o2[i][d] = 0.0f; }
    }

    int kend = qb * BQ + BQ;
    for (int k0 = 0; k0 < kend; k0 += BT) {
        // global -> regs
        int r = t >> 3;
        int c4 = (t & 7) * 4;
        float4 kv[4], vv[4];
        const float* ksrc = K + (size_t)(k0 + r) * (NKVH * HDIM) + kvh * HDIM + c4;
        const float* vsrc = V + (size_t)(k0 + r) * (NKVH * HDIM) + kvh * HDIM + c4;
        #pragma unroll
        for (int s = 0; s < 4; ++s) {
            kv[s] = *(const float4*)(ksrc + s * 32);
            vv[s] = *(const float4*)(vsrc + s * 32);
        }
        __syncthreads();                     // prev tile LDS reads done
        #pragma unroll
        for (int s = 0; s < 4; ++s) {
            *(float4*)&Ks[r][c4 + s * 32] = kv[s];
            *(float4*)&Vs[r][c4 + s * 32] = vv[s];
        }
        __syncthreads();                     // K/V (and first-iter Q) visible

        // scores: rows ty*4+i, cols tx*2+j
        float s1[4][2] = {{0,0},{0,0},{0,0},{0,0}};
        float s2[4][2] = {{0,0},{0,0},{0,0},{0,0}};
        #pragma unroll
        for (int d0 = 0; d0 < HHALF; d0 += 4) {
            float4 ka[2], kb2[2];
            #pragma unroll
            for (int j = 0; j < 2; ++j) {
                ka[j]  = *(const float4*)&Ks[tx * 2 + j][d0];
                kb2[j] = *(const float4*)&Ks[tx * 2 + j][HHALF + d0];
            }
            #pragma unroll
            for (int i = 0; i < 4; ++i) {
                float4 qa = *(const float4*)&Qs[ty * 4 + i][d0];
                float4 qb2 = *(const float4*)&Qs[ty * 4 + i][HHALF + d0];
                #pragma unroll
                for (int j = 0; j < 2; ++j) {
                    s1[i][j] += qa.x*ka[j].x + qa.y*ka[j].y + qa.z*ka[j].z + qa.w*ka[j].w;
                    s2[i][j] += qb2.x*kb2[j].x + qb2.y*kb2[j].y + qb2.z*kb2[j].z + qb2.w*kb2[j].w;
                }
            }
        }
        // scale + causal mask
        #pragma unroll
        for (int i = 0; i < 4; ++i) {
            int rg = qb * BQ + ty * 4 + i;
            #pragma unroll
            for (int j = 0; j < 2; ++j) {
                int cg = k0 + tx * 2 + j;
                s1[i][j] *= SM_SCALE; s2[i][j] *= SM_SCALE;
                if (cg > rg) { s1[i][j] = -1e30f; s2[i][j] = -1e30f; }
            }
        }
        // online softmax (both halves); stats replicated across the 16 tx lanes
        float p1v[4][2], p2v[4][2], sc1[4], sc2[4];
        #pragma unroll
        for (int i = 0; i < 4; ++i) {
            float tm1 = fmaxf(s1[i][0], s1[i][1]);
            float tm2 = fmaxf(s2[i][0], s2[i][1]);
            #pragma unroll
            for (int m = 1; m < 16; m <<= 1) {
                tm1 = fmaxf(tm1, __shfl_xor(tm1, m, 64));
                tm2 = fmaxf(tm2, __shfl_xor(tm2, m, 64));
            }
            float mn1 = fmaxf(m1[i], tm1);
            float mn2 = fmaxf(m2[i], tm2);
            p1v[i][0] = __expf(s1[i][0] - mn1); p1v[i][1] = __expf(s1[i][1] - mn1);
            p2v[i][0] = __expf(s2[i][0] - mn2); p2v[i][1] = __expf(s2[i][1] - mn2);
            float ts1 = p1v[i][0] + p1v[i][1];
            float ts2 = p2v[i][0] + p2v[i][1];
            #pragma unroll
            for (int m = 1; m < 16; m <<= 1) {
                ts1 += __shfl_xor(ts1, m, 64);
                ts2 += __shfl_xor(ts2, m, 64);
            }
            sc1[i] = __expf(m1[i] - mn1);
            sc2[i] = __expf(m2[i] - mn2);
            l1[i] = l1[i] * sc1[i] + ts1;
            l2[i] = l2[i] * sc2[i] + ts2;
            m1[i] = mn1; m2[i] = mn2;
        }
        // P1 -> LDS
        #pragma unroll
        for (int i = 0; i < 4; ++i)
            #pragma unroll
            for (int j = 0; j < 2; ++j)
                Ps[ty * 4 + i][tx * 2 + j] = p1v[i][j];
        __syncthreads();
        // PV1: rows ty*4+i, dims tx*8..+8
        #pragma unroll
        for (int i = 0; i < 4; ++i)
            #pragma unroll
            for (int d = 0; d < 8; ++d) o1[i][d] *= sc1[i];
        #pragma unroll
        for (int kk = 0; kk < BT; ++kk) {
            float4 va = *(const float4*)&Vs[kk][tx * 8];
            float4 vb = *(const float4*)&Vs[kk][tx * 8 + 4];
            #pragma unroll
            for (int i = 0; i < 4; ++i) {
                float p = Ps[ty * 4 + i][kk];
                o1[i][0] += p * va.x; o1[i][1] += p * va.y; o1[i][2] += p * va.z; o1[i][3] += p * va.w;
                o1[i][4] += p * vb.x; o1[i][5] += p * vb.y; o1[i][6] += p * vb.z; o1[i][7] += p * vb.w;
            }
        }
        __syncthreads();
        // P2 -> LDS
        #pragma unroll
        for (int i = 0; i < 4; ++i)
            #pragma unroll
            for (int j = 0; j < 2; ++j)
                Ps[ty * 4 + i][tx * 2 + j] = p2v[i][j];
        __syncthreads();
        // PV2
        #pragma unroll
        for (int i = 0; i < 4; ++i)
            #pragma unroll
            for (int d = 0; d < 8; ++d) o2[i][d] *= sc2[i];
        #pragma unroll
        for (int kk = 0; kk < BT; ++kk) {
            float4 va = *(const float4*)&Vs[kk][tx * 8];
            float4 vb = *(const float4*)&Vs[kk][tx * 8 + 4];
            #pragma unroll
            for (int i = 0; i < 4; ++i) {
                float p = Ps[ty * 4 + i][kk];
                o2[i][0] += p * va.x; o2[i][1] += p * va.y; o2[i][2] += p * va.z; o2[i][3] += p * va.w;
                o2[i][4] += p * vb.x; o2[i][5] += p * vb.y; o2[i][6] += p * vb.z; o2[i][7] += p * vb.w;
            }
        }
    }

    // epilogue: out = a1@V - LAMB * a2@V
    #pragma unroll
    for (int i = 0; i < 4; ++i) {
        int rg = qb * BQ + ty * 4 + i;
        float inv1 = 1.0f / l1[i];
        float inv2 = 1.0f / l2[i];
        float* dst = O + (size_t)rg * DIMSZ + h * HDIM + tx * 8;
        float4 w0, w1v;
        w0.x = o1[i][0]*inv1 - LAMB*o2[i][0]*inv2;
        w0.y = o1[i][1]*inv1 - LAMB*o2[i][1]*inv2;
        w0.z = o1[i][2]*inv1 - LAMB*o2[i][2]*inv2;
        w0.w = o1[i][3]*inv1 - LAMB*o2[i][3]*inv2;
        w1v.x = o1[i][4]*inv1 - LAMB*o2[i][4]*inv2;
        w1v.y = o1[i][5]*inv1 - LAMB*o2[i][5]*inv2;
        w1v.z = o1[i][6]*inv1 - LAMB*o2[i][6]*inv2;
        w1v.w = o1[i][7]*inv1 - LAMB*o2[i][7]*inv2;
        *(float4*)dst = w0;
        *(float4*)(dst + 4) = w1v;
    }
}

extern "C" void kernel_launch(void* const* d_in, const int* in_sizes, int n_in,
                              void* d_out, int out_size, void* d_ws, size_t ws_size,
                              hipStream_t stream)
{
    const float* x      = (const float*)d_in[0];
    const float* fcos   = (const float*)d_in[1];
    const float* fsin   = (const float*)d_in[2];
    const float* attn_w = (const float*)d_in[3];
    const float* wq     = (const float*)d_in[4];
    const float* wk     = (const float*)d_in[5];
    const float* wv     = (const float*)d_in[6];
    const float* wo     = (const float*)d_in[7];
    const float* ffn_w  = (const float*)d_in[8];
    const float* w1     = (const float*)d_in[9];
    const float* w2     = (const float*)d_in[10];
    const float* w3     = (const float*)d_in[11];
    float* out = (float*)d_out;
    float* ws  = (float*)d_ws;

    float* h   = ws;                         // 4M floats
    float* q   = ws + (4u << 20);            // 4M
    float* kb  = ws + (8u << 20);            // 2M
    float* vb  = ws + (10u << 20);           // 2M
    float* att = ws + (12u << 20);           // 4M
    float* f   = h;                          // reuse (h dead after QKV)
    float* u   = q;                          // reuse q..att (11.5M <= 12M)

    dim3 blk(256);
    rmsnorm_kernel<<<LSEQ, blk, 0, stream>>>(x, attn_w, h);
    gemm_f32<0><<<dim3(16, 16), blk, 0, stream>>>(h, wq, q, nullptr, 2048, 2048, 2048);
    gemm_f32<0><<<dim3(8, 16), blk, 0, stream>>>(h, wk, kb, nullptr, 2048, 1024, 2048);
    gemm_f32<0><<<dim3(8, 16), blk, 0, stream>>>(h, wv, vb, nullptr, 2048, 1024, 2048);
    rope_kernel<<<(LSEQ * NHEADS * 64) / 256, blk, 0, stream>>>(q, fcos, fsin, 4);
    rope_kernel<<<(LSEQ * NKVH * 64) / 256, blk, 0, stream>>>(kb, fcos, fsin, 3);
    attn_kernel<<<dim3(LSEQ / 64, NHEADS), blk, 0, stream>>>(q, kb, vb, att);
    gemm_f32<1><<<dim3(16, 16), blk, 0, stream>>>(att, wo, out, x, 2048, 2048, 2048);
    rmsnorm_kernel<<<LSEQ, blk, 0, stream>>>(out, ffn_w, f);
    gemm_f32<0><<<dim3(44, 16), blk, 0, stream>>>(f, w1, u, nullptr, 2048, 5632, 2048);
    gemm_f32<2><<<dim3(44, 16), blk, 0, stream>>>(f, w3, u, u, 2048, 5632, 2048);
    gemm_f32<1><<<dim3(16, 16), blk, 0, stream>>>(u, w2, out, out, 2048, 2048, 5632);
}

// Round 4
// 1914.154 us; speedup vs baseline: 2.8751x; 2.8751x over previous
//
#include <hip/hip_runtime.h>
#include <hip/hip_bf16.h>

#define DIMSZ 2048
#define LSEQ 2048
#define NHEADS 16
#define NKVH 8
#define HDIM 128
#define HHALF 64
#define EPSV 1e-5f
#define LAMB 0.2f
#define SM_SCALE 0.125f

typedef __attribute__((ext_vector_type(8))) short bf16x8;
typedef __attribute__((ext_vector_type(4))) float f32x4;
typedef __hip_bfloat16 bf16;

__device__ __forceinline__ void gload_lds16(const void* g, void* l) {
    __builtin_amdgcn_global_load_lds((const __attribute__((address_space(1))) void*)g,
                                     (__attribute__((address_space(3))) void*)l, 16, 0, 0);
}

template<typename T> __device__ __forceinline__ T cvt_out(float v);
template<> __device__ __forceinline__ float cvt_out<float>(float v) { return v; }
template<> __device__ __forceinline__ bf16  cvt_out<bf16>(float v)  { return __float2bfloat16(v); }

// ---------------- RMSNorm: fp32 in, bf16 out ----------------
__global__ __launch_bounds__(256) void rmsnorm_kernel(const float* __restrict__ x,
                                                      const float* __restrict__ w,
                                                      bf16* __restrict__ out)
{
    int row = blockIdx.x;
    int t = threadIdx.x;
    const float* xr = x + (size_t)row * DIMSZ;
    float4 v0 = ((const float4*)xr)[t];
    float4 v1 = ((const float4*)xr)[t + 256];
    float s = v0.x*v0.x + v0.y*v0.y + v0.z*v0.z + v0.w*v0.w
            + v1.x*v1.x + v1.y*v1.y + v1.z*v1.z + v1.w*v1.w;
    #pragma unroll
    for (int m = 1; m < 64; m <<= 1) s += __shfl_xor(s, m, 64);
    __shared__ float red[4];
    int wid = t >> 6;
    if ((t & 63) == 0) red[wid] = s;
    __syncthreads();
    float tot = red[0] + red[1] + red[2] + red[3];
    float inv = rsqrtf(tot * (1.0f / DIMSZ) + EPSV);
    float4 w0 = ((const float4*)w)[t];
    float4 w1v = ((const float4*)w)[t + 256];
    bf16* orow = out + (size_t)row * DIMSZ;
    orow[t*4 + 0] = __float2bfloat16(v0.x*inv*w0.x);
    orow[t*4 + 1] = __float2bfloat16(v0.y*inv*w0.y);
    orow[t*4 + 2] = __float2bfloat16(v0.z*inv*w0.z);
    orow[t*4 + 3] = __float2bfloat16(v0.w*inv*w0.w);
    orow[1024 + t*4 + 0] = __float2bfloat16(v1.x*inv*w1v.x);
    orow[1024 + t*4 + 1] = __float2bfloat16(v1.y*inv*w1v.y);
    orow[1024 + t*4 + 2] = __float2bfloat16(v1.z*inv*w1v.z);
    orow[1024 + t*4 + 3] = __float2bfloat16(v1.w*inv*w1v.w);
}

// ---------------- transpose + cast: in fp32 [K][N] -> out bf16 [N][K] ----------------
__global__ __launch_bounds__(256) void tcast_kernel(const float* __restrict__ in,
                                                    bf16* __restrict__ out,
                                                    int K, int N)
{
    __shared__ float tile[32][33];
    int bx = blockIdx.x, by = blockIdx.y;       // bx: N-tile, by: K-tile
    int tx = threadIdx.x & 31, tr = threadIdx.x >> 5;  // tr 0..7
    const float* src = in + (size_t)(by*32 + tr) * N + bx*32 + tx;
    #pragma unroll
    for (int r = 0; r < 32; r += 8)
        tile[tr + r][tx] = src[(size_t)r * N];
    __syncthreads();
    bf16* dst = out + (size_t)(bx*32 + tr) * K + by*32 + tx;
    #pragma unroll
    for (int r = 0; r < 32; r += 8)
        dst[(size_t)r * K] = __float2bfloat16(tile[tx][tr + r]);
}

// ---------------- RoPE (in-place fp32, interleaved pairs) ----------------
__global__ __launch_bounds__(256) void rope_kernel(float* __restrict__ buf,
                                                   const float* __restrict__ cosT,
                                                   const float* __restrict__ sinT,
                                                   int log2nh)
{
    int idx = blockIdx.x * 256 + threadIdx.x;
    int j = idx & 63;
    int hl = idx >> 6;
    int l = hl >> log2nh;
    float c = cosT[l * 64 + j];
    float s = sinT[l * 64 + j];
    float2 v = ((float2*)buf)[idx];
    float2 r;
    r.x = v.x * c - v.y * s;
    r.y = v.x * s + v.y * c;
    ((float2*)buf)[idx] = r;
}

// ---------------- bf16 MFMA GEMM: C[M,N] = A[M,K] * BT[N,K]^T (+ epilogue) ----------------
// EPI 0: C = acc ; EPI 1: C = R + acc ; EPI 2: C = silu(R) * acc
template<int EPI, typename CT>
__global__ __launch_bounds__(256) void gemm_bf16(const bf16* __restrict__ A,
                                                 const bf16* __restrict__ BT,
                                                 CT* __restrict__ C,
                                                 const float* __restrict__ R,
                                                 int M, int N, int K)
{
    constexpr int BK = 32;
    __shared__ alignas(16) bf16 As[128 * BK];
    __shared__ alignas(16) bf16 Bs[128 * BK];
    int t = threadIdx.x;
    int lane = t & 63, wid = t >> 6;
    int wr = wid >> 1, wc = wid & 1;            // 2x2 wave grid, each wave 64x64
    int row0 = blockIdx.y * 128, col0 = blockIdx.x * 128;

    f32x4 acc[4][4];
    #pragma unroll
    for (int i = 0; i < 4; ++i)
        #pragma unroll
        for (int j = 0; j < 4; ++j)
            acc[i][j] = (f32x4){0.f, 0.f, 0.f, 0.f};

    for (int k0 = 0; k0 < K; k0 += BK) {
        __syncthreads();                        // prev-iter LDS reads done
        #pragma unroll
        for (int s = 0; s < 2; ++s) {
            int c = s * 256 + t;                // chunk id; lds off = c*16 (wave-uniform base + lane*16)
            int row = c >> 2, kc = c & 3;
            gload_lds16(A  + (size_t)(row0 + row) * K + k0 + kc * 8, (char*)As + c * 16);
            gload_lds16(BT + (size_t)(col0 + row) * K + k0 + kc * 8, (char*)Bs + c * 16);
        }
        __syncthreads();                        // drains vmcnt before compute

        bf16x8 a[4], b[4];
        int ch = lane >> 4;
        #pragma unroll
        for (int i = 0; i < 4; ++i) {
            int ra = wr * 64 + i * 16 + (lane & 15);
            int rb = wc * 64 + i * 16 + (lane & 15);
            a[i] = *(const bf16x8*)((const char*)As + ra * 64 + ch * 16);
            b[i] = *(const bf16x8*)((const char*)Bs + rb * 64 + ch * 16);
        }
        #pragma unroll
        for (int i = 0; i < 4; ++i)
            #pragma unroll
            for (int j = 0; j < 4; ++j)
                acc[i][j] = __builtin_amdgcn_mfma_f32_16x16x32_bf16(a[i], b[j], acc[i][j], 0, 0, 0);
    }

    int rl = lane >> 4;                          // D: row=(lane>>4)*4+reg, col=lane&15
    int cl = lane & 15;
    #pragma unroll
    for (int i = 0; i < 4; ++i) {
        #pragma unroll
        for (int j = 0; j < 4; ++j) {
            #pragma unroll
            for (int r = 0; r < 4; ++r) {
                int row = row0 + wr * 64 + i * 16 + rl * 4 + r;
                int col = col0 + wc * 64 + j * 16 + cl;
                size_t idx = (size_t)row * N + col;
                float v = acc[i][j][r];
                if (EPI == 1) v += R[idx];
                else if (EPI == 2) { float uv = R[idx]; v = (uv / (1.0f + __expf(-uv))) * v; }
                C[idx] = cvt_out<CT>(v);
            }
        }
    }
}

// ---------------- Differential GQA flash attention (fp32 math, bf16 out) ----------------
// grid (L/32, NH) with reversed qb; block 256
__global__ __launch_bounds__(256) void attn_kernel(const float* __restrict__ Q,
                                                   const float* __restrict__ K,
                                                   const float* __restrict__ V,
                                                   bf16* __restrict__ O)
{
    constexpr int BQ = 32, BT = 32, QS = 132, KS = 132;
    int qb = gridDim.x - 1 - blockIdx.x;        // heavy blocks first
    int h = blockIdx.y;
    int kvh = h >> 1;
    int t = threadIdx.x;
    int tx = t & 15, ty = t >> 4;               // ty 0..15 -> 2 rows each

    __shared__ float Qs[BQ][QS];
    __shared__ float Ks[BT][KS];
    __shared__ float Vs[BT][128];
    __shared__ float P1[BQ][33];
    __shared__ float P2[BQ][33];

    {   // load Q tile (32 x 128)
        int r = t >> 3, c0 = (t & 7) * 4;
        const float* src = Q + (size_t)(qb * BQ + r) * (NHEADS * HDIM) + h * HDIM;
        #pragma unroll
        for (int s = 0; s < 4; ++s)
            *(float4*)&Qs[r][c0 + s * 32] = *(const float4*)(src + c0 + s * 32);
    }

    float m1[2], l1[2], m2[2], l2[2];
    float o1[2][8], o2[2][8];
    #pragma unroll
    for (int i = 0; i < 2; ++i) {
        m1[i] = -1e30f; m2[i] = -1e30f; l1[i] = 0.0f; l2[i] = 0.0f;
        #pragma unroll
        for (int d = 0; d < 8; ++d) { o1[i][d] = 0.0f; o2[i][d] = 0.0f; }
    }

    int nt = qb + 1;
    for (int it = 0; it < nt; ++it) {
        int k0 = it * BT;
        int r = t >> 3, c4 = (t & 7) * 4;
        float4 kv[4], vv[4];
        const float* ksrc = K + (size_t)(k0 + r) * (NKVH * HDIM) + kvh * HDIM;
        const float* vsrc = V + (size_t)(k0 + r) * (NKVH * HDIM) + kvh * HDIM;
        #pragma unroll
        for (int s = 0; s < 4; ++s) {
            kv[s] = *(const float4*)(ksrc + c4 + s * 32);
            vv[s] = *(const float4*)(vsrc + c4 + s * 32);
        }
        __syncthreads();                         // prev-tile LDS reads (Ks/Vs/P) done
        #pragma unroll
        for (int s = 0; s < 4; ++s) {
            *(float4*)&Ks[r][c4 + s * 32] = kv[s];
            *(float4*)&Vs[r][c4 + s * 32] = vv[s];
        }
        __syncthreads();

        // scores: rows ty*2+i, cols tx + 16*j (conflict-free Ks reads at stride 132)
        float s1[2][2] = {{0,0},{0,0}};
        float s2[2][2] = {{0,0},{0,0}};
        #pragma unroll
        for (int d0 = 0; d0 < HHALF; d0 += 4) {
            float4 ka[2], kb2[2];
            #pragma unroll
            for (int j = 0; j < 2; ++j) {
                ka[j]  = *(const float4*)&Ks[tx + 16 * j][d0];
                kb2[j] = *(const float4*)&Ks[tx + 16 * j][HHALF + d0];
            }
            #pragma unroll
            for (int i = 0; i < 2; ++i) {
                float4 qa  = *(const float4*)&Qs[ty * 2 + i][d0];
                float4 qb2 = *(const float4*)&Qs[ty * 2 + i][HHALF + d0];
                #pragma unroll
                for (int j = 0; j < 2; ++j) {
                    s1[i][j] += qa.x*ka[j].x + qa.y*ka[j].y + qa.z*ka[j].z + qa.w*ka[j].w;
                    s2[i][j] += qb2.x*kb2[j].x + qb2.y*kb2[j].y + qb2.z*kb2[j].z + qb2.w*kb2[j].w;
                }
            }
        }
        #pragma unroll
        for (int i = 0; i < 2; ++i) {
            int rg = qb * BQ + ty * 2 + i;
            #pragma unroll
            for (int j = 0; j < 2; ++j) {
                int cg = k0 + tx + 16 * j;
                s1[i][j] *= SM_SCALE; s2[i][j] *= SM_SCALE;
                if (cg > rg) { s1[i][j] = -1e30f; s2[i][j] = -1e30f; }
            }
        }
        float p1v[2][2], p2v[2][2], sc1[2], sc2[2];
        #pragma unroll
        for (int i = 0; i < 2; ++i) {
            float tm1 = fmaxf(s1[i][0], s1[i][1]);
            float tm2 = fmaxf(s2[i][0], s2[i][1]);
            #pragma unroll
            for (int m = 1; m < 16; m <<= 1) {
                tm1 = fmaxf(tm1, __shfl_xor(tm1, m, 64));
                tm2 = fmaxf(tm2, __shfl_xor(tm2, m, 64));
            }
            float mn1 = fmaxf(m1[i], tm1);
            float mn2 = fmaxf(m2[i], tm2);
            p1v[i][0] = __expf(s1[i][0] - mn1); p1v[i][1] = __expf(s1[i][1] - mn1);
            p2v[i][0] = __expf(s2[i][0] - mn2); p2v[i][1] = __expf(s2[i][1] - mn2);
            float ts1 = p1v[i][0] + p1v[i][1];
            float ts2 = p2v[i][0] + p2v[i][1];
            #pragma unroll
            for (int m = 1; m < 16; m <<= 1) {
                ts1 += __shfl_xor(ts1, m, 64);
                ts2 += __shfl_xor(ts2, m, 64);
            }
            sc1[i] = __expf(m1[i] - mn1);
            sc2[i] = __expf(m2[i] - mn2);
            l1[i] = l1[i] * sc1[i] + ts1;
            l2[i] = l2[i] * sc2[i] + ts2;
            m1[i] = mn1; m2[i] = mn2;
        }
        #pragma unroll
        for (int i = 0; i < 2; ++i)
            #pragma unroll
            for (int j = 0; j < 2; ++j) {
                P1[ty * 2 + i][tx + 16 * j] = p1v[i][j];
                P2[ty * 2 + i][tx + 16 * j] = p2v[i][j];
            }
        __syncthreads();                         // P visible

        #pragma unroll
        for (int i = 0; i < 2; ++i)
            #pragma unroll
            for (int d = 0; d < 8; ++d) { o1[i][d] *= sc1[i]; o2[i][d] *= sc2[i]; }

        // merged PV: lane owns dims tx*4..+3 and 64+tx*4..+3 (conflict-free Vs reads)
        #pragma unroll
        for (int kk = 0; kk < BT; ++kk) {
            float4 va = *(const float4*)&Vs[kk][tx * 4];
            float4 vb = *(const float4*)&Vs[kk][64 + tx * 4];
            #pragma unroll
            for (int i = 0; i < 2; ++i) {
                float p1 = P1[ty * 2 + i][kk];
                float p2 = P2[ty * 2 + i][kk];
                o1[i][0] += p1 * va.x; o1[i][1] += p1 * va.y; o1[i][2] += p1 * va.z; o1[i][3] += p1 * va.w;
                o1[i][4] += p1 * vb.x; o1[i][5] += p1 * vb.y; o1[i][6] += p1 * vb.z; o1[i][7] += p1 * vb.w;
                o2[i][0] += p2 * va.x; o2[i][1] += p2 * va.y; o2[i][2] += p2 * va.z; o2[i][3] += p2 * va.w;
                o2[i][4] += p2 * vb.x; o2[i][5] += p2 * vb.y; o2[i][6] += p2 * vb.z; o2[i][7] += p2 * vb.w;
            }
        }
    }

    #pragma unroll
    for (int i = 0; i < 2; ++i) {
        int rg = qb * BQ + ty * 2 + i;
        float inv1 = 1.0f / l1[i];
        float inv2 = 1.0f / l2[i];
        bf16* dst = O + (size_t)rg * DIMSZ + h * HDIM;
        #pragma unroll
        for (int d = 0; d < 4; ++d) {
            dst[tx * 4 + d]      = __float2bfloat16(o1[i][d]     * inv1 - LAMB * o2[i][d]     * inv2);
            dst[64 + tx * 4 + d] = __float2bfloat16(o1[i][d + 4] * inv1 - LAMB * o2[i][d + 4] * inv2);
        }
    }
}

extern "C" void kernel_launch(void* const* d_in, const int* in_sizes, int n_in,
                              void* d_out, int out_size, void* d_ws, size_t ws_size,
                              hipStream_t stream)
{
    const float* x      = (const float*)d_in[0];
    const float* fcos   = (const float*)d_in[1];
    const float* fsin   = (const float*)d_in[2];
    const float* attn_w = (const float*)d_in[3];
    const float* wq     = (const float*)d_in[4];
    const float* wk     = (const float*)d_in[5];
    const float* wv     = (const float*)d_in[6];
    const float* wo     = (const float*)d_in[7];
    const float* ffn_w  = (const float*)d_in[8];
    const float* w1     = (const float*)d_in[9];
    const float* w2     = (const float*)d_in[10];
    const float* w3     = (const float*)d_in[11];
    float* out = (float*)d_out;
    char*  wsb = (char*)d_ws;

    // ws layout (bytes): region0 [0,48M): h(8M) q(16M) k(8M) v(8M) att(8M); u overlaps [0,46.1M)
    bf16*  h   = (bf16*) (wsb + 0);
    float* q   = (float*)(wsb + (size_t)( 8u << 20));
    float* kb  = (float*)(wsb + (size_t)(24u << 20));
    float* vb  = (float*)(wsb + (size_t)(32u << 20));
    bf16*  att = (bf16*) (wsb + (size_t)(40u << 20));
    float* u   = (float*)(wsb + 0);
    bf16*  f   = (bf16*) (wsb + (size_t)(48u << 20));
    bf16*  g   = (bf16*) (wsb + (size_t)(56u << 20));
    bf16*  W   = (bf16*) (wsb + (size_t)(80u << 20));   // reused transposed-weight slot (23.1M max)

    dim3 blk(256);

    rmsnorm_kernel<<<LSEQ, blk, 0, stream>>>(x, attn_w, h);

    tcast_kernel<<<dim3(64, 64), blk, 0, stream>>>(wq, W, 2048, 2048);
    gemm_bf16<0, float><<<dim3(16, 16), blk, 0, stream>>>(h, W, q, nullptr, 2048, 2048, 2048);
    tcast_kernel<<<dim3(32, 64), blk, 0, stream>>>(wk, W, 2048, 1024);
    gemm_bf16<0, float><<<dim3(8, 16), blk, 0, stream>>>(h, W, kb, nullptr, 2048, 1024, 2048);
    tcast_kernel<<<dim3(32, 64), blk, 0, stream>>>(wv, W, 2048, 1024);
    gemm_bf16<0, float><<<dim3(8, 16), blk, 0, stream>>>(h, W, vb, nullptr, 2048, 1024, 2048);

    rope_kernel<<<(LSEQ * NHEADS * 64) / 256, blk, 0, stream>>>(q, fcos, fsin, 4);
    rope_kernel<<<(LSEQ * NKVH * 64) / 256, blk, 0, stream>>>(kb, fcos, fsin, 3);

    attn_kernel<<<dim3(LSEQ / 32, NHEADS), blk, 0, stream>>>(q, kb, vb, att);

    tcast_kernel<<<dim3(64, 64), blk, 0, stream>>>(wo, W, 2048, 2048);
    gemm_bf16<1, float><<<dim3(16, 16), blk, 0, stream>>>(att, W, out, x, 2048, 2048, 2048);

    rmsnorm_kernel<<<LSEQ, blk, 0, stream>>>(out, ffn_w, f);

    tcast_kernel<<<dim3(176, 64), blk, 0, stream>>>(w1, W, 2048, 5632);
    gemm_bf16<0, float><<<dim3(44, 16), blk, 0, stream>>>(f, W, u, nullptr, 2048, 5632, 2048);
    tcast_kernel<<<dim3(176, 64), blk, 0, stream>>>(w3, W, 2048, 5632);
    gemm_bf16<2, bf16><<<dim3(44, 16), blk, 0, stream>>>(f, W, g, u, 2048, 5632, 2048);
    tcast_kernel<<<dim3(64, 176), blk, 0, stream>>>(w2, W, 5632, 2048);
    gemm_bf16<1, float><<<dim3(16, 16), blk, 0, stream>>>(g, W, out, out, 2048, 2048, 5632);
}

// Round 5
// 937.995 us; speedup vs baseline: 5.8673x; 2.0407x over previous
//
#include <hip/hip_runtime.h>
#include <hip/hip_bf16.h>

#define DIMSZ 2048
#define LSEQ 2048
#define NHEADS 16
#define NKVH 8
#define HDIM 128
#define HHALF 64
#define EPSV 1e-5f
#define LAMB 0.2f
#define SM_SCALE 0.125f

typedef __attribute__((ext_vector_type(8))) short bf16x8;
typedef __attribute__((ext_vector_type(4))) float f32x4;
typedef __hip_bfloat16 bf16;

__device__ __forceinline__ void gload_lds16(const void* g, void* l) {
    __builtin_amdgcn_global_load_lds((const __attribute__((address_space(1))) void*)g,
                                     (__attribute__((address_space(3))) void*)l, 16, 0, 0);
}

template<typename T> __device__ __forceinline__ T cvt_out(float v);
template<> __device__ __forceinline__ float cvt_out<float>(float v) { return v; }
template<> __device__ __forceinline__ bf16  cvt_out<bf16>(float v)  { return __float2bfloat16(v); }

// ---------------- RMSNorm: fp32 in, bf16 out ----------------
__global__ __launch_bounds__(256) void rmsnorm_kernel(const float* __restrict__ x,
                                                      const float* __restrict__ w,
                                                      bf16* __restrict__ out)
{
    int row = blockIdx.x;
    int t = threadIdx.x;
    const float* xr = x + (size_t)row * DIMSZ;
    float4 v0 = ((const float4*)xr)[t];
    float4 v1 = ((const float4*)xr)[t + 256];
    float s = v0.x*v0.x + v0.y*v0.y + v0.z*v0.z + v0.w*v0.w
            + v1.x*v1.x + v1.y*v1.y + v1.z*v1.z + v1.w*v1.w;
    #pragma unroll
    for (int m = 1; m < 64; m <<= 1) s += __shfl_xor(s, m, 64);
    __shared__ float red[4];
    int wid = t >> 6;
    if ((t & 63) == 0) red[wid] = s;
    __syncthreads();
    float tot = red[0] + red[1] + red[2] + red[3];
    float inv = rsqrtf(tot * (1.0f / DIMSZ) + EPSV);
    float4 w0 = ((const float4*)w)[t];
    float4 w1v = ((const float4*)w)[t + 256];
    bf16* orow = out + (size_t)row * DIMSZ;
    orow[t*4 + 0] = __float2bfloat16(v0.x*inv*w0.x);
    orow[t*4 + 1] = __float2bfloat16(v0.y*inv*w0.y);
    orow[t*4 + 2] = __float2bfloat16(v0.z*inv*w0.z);
    orow[t*4 + 3] = __float2bfloat16(v0.w*inv*w0.w);
    orow[1024 + t*4 + 0] = __float2bfloat16(v1.x*inv*w1v.x);
    orow[1024 + t*4 + 1] = __float2bfloat16(v1.y*inv*w1v.y);
    orow[1024 + t*4 + 2] = __float2bfloat16(v1.z*inv*w1v.z);
    orow[1024 + t*4 + 3] = __float2bfloat16(v1.w*inv*w1v.w);
}

// ---------------- transpose + cast: in fp32 [K][N] -> out bf16 [N][K] ----------------
__global__ __launch_bounds__(256) void tcast_kernel(const float* __restrict__ in,
                                                    bf16* __restrict__ out,
                                                    int K, int N)
{
    __shared__ float tile[32][33];
    int bx = blockIdx.x, by = blockIdx.y;       // bx: N-tile, by: K-tile
    int tx = threadIdx.x & 31, tr = threadIdx.x >> 5;  // tr 0..7
    const float* src = in + (size_t)(by*32 + tr) * N + bx*32 + tx;
    #pragma unroll
    for (int r = 0; r < 32; r += 8)
        tile[tr + r][tx] = src[(size_t)r * N];
    __syncthreads();
    bf16* dst = out + (size_t)(bx*32 + tr) * K + by*32 + tx;
    #pragma unroll
    for (int r = 0; r < 32; r += 8)
        dst[(size_t)r * K] = __float2bfloat16(tile[tx][tr + r]);
}

// ---------------- RoPE + cast to bf16 (separate output buffer) ----------------
__global__ __launch_bounds__(256) void rope_cast_kernel(const float* __restrict__ buf,
                                                        const float* __restrict__ cosT,
                                                        const float* __restrict__ sinT,
                                                        bf16* __restrict__ out,
                                                        int log2nh)
{
    int idx = blockIdx.x * 256 + threadIdx.x;   // (l, head, j), j fastest
    int j = idx & 63;
    int hl = idx >> 6;
    int l = hl >> log2nh;
    float c = cosT[l * 64 + j];
    float s = sinT[l * 64 + j];
    float2 v = ((const float2*)buf)[idx];
    __hip_bfloat162 rr;
    rr.x = __float2bfloat16(v.x * c - v.y * s);
    rr.y = __float2bfloat16(v.x * s + v.y * c);
    ((__hip_bfloat162*)out)[idx] = rr;
}

// ---------------- bf16 MFMA GEMM: C[M,N] = A[M,K] * BT[N,K]^T (+ epilogue) ----------------
// EPI 0: C = acc ; EPI 1: C = R + acc ; EPI 2: C = silu(R) * acc
template<int EPI, typename CT>
__global__ __launch_bounds__(256) void gemm_bf16(const bf16* __restrict__ A,
                                                 const bf16* __restrict__ BT,
                                                 CT* __restrict__ C,
                                                 const float* __restrict__ R,
                                                 int M, int N, int K)
{
    constexpr int BK = 32;
    __shared__ alignas(16) bf16 As[128 * BK];
    __shared__ alignas(16) bf16 Bs[128 * BK];
    int t = threadIdx.x;
    int lane = t & 63, wid = t >> 6;
    int wr = wid >> 1, wc = wid & 1;            // 2x2 wave grid, each wave 64x64
    int row0 = blockIdx.y * 128, col0 = blockIdx.x * 128;

    f32x4 acc[4][4];
    #pragma unroll
    for (int i = 0; i < 4; ++i)
        #pragma unroll
        for (int j = 0; j < 4; ++j)
            acc[i][j] = (f32x4){0.f, 0.f, 0.f, 0.f};

    for (int k0 = 0; k0 < K; k0 += BK) {
        __syncthreads();                        // prev-iter LDS reads done
        #pragma unroll
        for (int s = 0; s < 2; ++s) {
            int c = s * 256 + t;                // chunk id
            int row = c >> 2, kc = c & 3;
            gload_lds16(A  + (size_t)(row0 + row) * K + k0 + kc * 8, (char*)As + c * 16);
            gload_lds16(BT + (size_t)(col0 + row) * K + k0 + kc * 8, (char*)Bs + c * 16);
        }
        __syncthreads();                        // drains vmcnt before compute

        bf16x8 a[4], b[4];
        int ch = lane >> 4;
        #pragma unroll
        for (int i = 0; i < 4; ++i) {
            int ra = wr * 64 + i * 16 + (lane & 15);
            int rb = wc * 64 + i * 16 + (lane & 15);
            a[i] = *(const bf16x8*)((const char*)As + ra * 64 + ch * 16);
            b[i] = *(const bf16x8*)((const char*)Bs + rb * 64 + ch * 16);
        }
        #pragma unroll
        for (int i = 0; i < 4; ++i)
            #pragma unroll
            for (int j = 0; j < 4; ++j)
                acc[i][j] = __builtin_amdgcn_mfma_f32_16x16x32_bf16(a[i], b[j], acc[i][j], 0, 0, 0);
    }

    int rl = lane >> 4;                          // D: row=(lane>>4)*4+reg, col=lane&15
    int cl = lane & 15;
    #pragma unroll
    for (int i = 0; i < 4; ++i) {
        #pragma unroll
        for (int j = 0; j < 4; ++j) {
            #pragma unroll
            for (int r = 0; r < 4; ++r) {
                int row = row0 + wr * 64 + i * 16 + rl * 4 + r;
                int col = col0 + wc * 64 + j * 16 + cl;
                size_t idx = (size_t)row * N + col;
                float v = acc[i][j][r];
                if (EPI == 1) v += R[idx];
                else if (EPI == 2) { float uv = R[idx]; v = (uv / (1.0f + __expf(-uv))) * v; }
                C[idx] = cvt_out<CT>(v);
            }
        }
    }
}

// ---------------- Differential GQA flash attention, bf16 MFMA ----------------
// Qb [L][NH*128] bf16 (RoPE'd) ; Kb [L][NKV*128] bf16 (RoPE'd) ; Vt [NKV*128][L] bf16
// grid (L/64, NH) reversed qb; block 256 = 4 waves, each wave owns 16 q-rows.
__global__ __launch_bounds__(256) void attn_mfma_kernel(const bf16* __restrict__ Qb,
                                                        const bf16* __restrict__ Kb,
                                                        const bf16* __restrict__ Vt,
                                                        bf16* __restrict__ O)
{
    int qb = (int)gridDim.x - 1 - (int)blockIdx.x;   // heavy blocks first
    int h = blockIdx.y;
    int kvh = h >> 1;
    int t = threadIdx.x;
    int lane = t & 63, w = t >> 6;
    int lr = lane & 15;          // A-row / B-col selector
    int lk = lane >> 4;          // k-chunk selector (0..3)

    // K tile row-major [64 key][128 d], V tile col-major [128 d][64 key], P [64 row][64 key]
    // all bf16, all XOR-swizzled on 16B blocks to kill same-bank row-stride conflicts (G4).
    __shared__ alignas(16) bf16 Ksm[64 * 128];
    __shared__ alignas(16) bf16 Vsm[128 * 64];
    __shared__ alignas(16) bf16 Psm[2][64 * 64];

    // Q fragments in registers: qf[s] covers d = s*32 + lk*8 .. +8 of row qb*64+w*16+lr
    bf16x8 qf[4];
    {
        const char* qrow = (const char*)Qb + ((size_t)(qb * 64 + w * 16 + lr) * (NHEADS * HDIM) + h * HDIM) * 2;
        #pragma unroll
        for (int s = 0; s < 4; ++s)
            qf[s] = *(const bf16x8*)(qrow + (s * 32 + lk * 8) * 2);
    }

    f32x4 o1[8], o2[8];
    #pragma unroll
    for (int d = 0; d < 8; ++d) { o1[d] = (f32x4){0.f,0.f,0.f,0.f}; o2[d] = (f32x4){0.f,0.f,0.f,0.f}; }
    float m1[4], l1[4], m2[4], l2[4];
    #pragma unroll
    for (int r = 0; r < 4; ++r) { m1[r] = -1e30f; m2[r] = -1e30f; l1[r] = 0.f; l2[r] = 0.f; }

    int nt = qb + 1;
    for (int it = 0; it < nt; ++it) {
        int k0 = it * 64;
        // ---- stage K (16KB) + V (16KB): global -> regs -> swizzled LDS
        bf16x8 kreg[4], vreg[4];
        #pragma unroll
        for (int c4 = 0; c4 < 4; ++c4) {
            int c = c4 * 256 + t;                       // 0..1023
            int key = c >> 4, db = (c & 15) * 16;       // K chunk: row key, byte db
            kreg[c4] = *(const bf16x8*)((const char*)Kb
                        + (size_t)(k0 + key) * (NKVH * HDIM * 2) + kvh * HDIM * 2 + db);
            int d = c >> 3, kbyte = (c & 7) * 16;       // V chunk: row d, byte kbyte
            vreg[c4] = *(const bf16x8*)((const char*)Vt
                        + ((size_t)(kvh * HDIM + d) * LSEQ + k0) * 2 + kbyte);
        }
        __syncthreads();                                // prior tile's LDS reads done
        #pragma unroll
        for (int c4 = 0; c4 < 4; ++c4) {
            int c = c4 * 256 + t;
            int key = c >> 4, db = (c & 15) * 16;
            *(bf16x8*)((char*)Ksm + ((key * 256 + db) ^ ((key & 7) << 4))) = kreg[c4];
            int d = c >> 3, kbyte = (c & 7) * 16;
            *(bf16x8*)((char*)Vsm + ((d * 128 + kbyte) ^ ((d & 7) << 4))) = vreg[c4];
        }
        __syncthreads();                                // K/V visible

        // ---- QK^T (both halves): scores 16 rows x 64 keys per wave
        f32x4 s1a[4], s2a[4];
        #pragma unroll
        for (int ct = 0; ct < 4; ++ct) { s1a[ct] = (f32x4){0.f,0.f,0.f,0.f}; s2a[ct] = (f32x4){0.f,0.f,0.f,0.f}; }
        #pragma unroll
        for (int ct = 0; ct < 4; ++ct) {
            int key = ct * 16 + lr;
            int kswz = (key & 7) << 4;
            #pragma unroll
            for (int s = 0; s < 2; ++s) {
                bf16x8 kb1 = *(const bf16x8*)((const char*)Ksm + ((key * 256 + (s * 32 + lk * 8) * 2) ^ kswz));
                bf16x8 kb2 = *(const bf16x8*)((const char*)Ksm + ((key * 256 + (64 + s * 32 + lk * 8) * 2) ^ kswz));
                s1a[ct] = __builtin_amdgcn_mfma_f32_16x16x32_bf16(qf[s],     kb1, s1a[ct], 0, 0, 0);
                s2a[ct] = __builtin_amdgcn_mfma_f32_16x16x32_bf16(qf[2 + s], kb2, s2a[ct], 0, 0, 0);
            }
        }

        // ---- online softmax (rows = lk*4 + r, replicated over the 16 lr lanes)
        bool diag = (it == nt - 1);
        #pragma unroll
        for (int r = 0; r < 4; ++r) {
            int rowl = w * 16 + lk * 4 + r;             // block-local q-row
            int rg = qb * 64 + rowl;
            float v1[4], v2[4];
            #pragma unroll
            for (int ct = 0; ct < 4; ++ct) {
                v1[ct] = s1a[ct][r] * SM_SCALE;
                v2[ct] = s2a[ct][r] * SM_SCALE;
                if (diag) {
                    int cg = k0 + ct * 16 + lr;
                    if (cg > rg) { v1[ct] = -1e30f; v2[ct] = -1e30f; }
                }
            }
            float tm1 = fmaxf(fmaxf(v1[0], v1[1]), fmaxf(v1[2], v1[3]));
            float tm2 = fmaxf(fmaxf(v2[0], v2[1]), fmaxf(v2[2], v2[3]));
            #pragma unroll
            for (int msk = 1; msk < 16; msk <<= 1) {
                tm1 = fmaxf(tm1, __shfl_xor(tm1, msk, 64));
                tm2 = fmaxf(tm2, __shfl_xor(tm2, msk, 64));
            }
            float mn1 = fmaxf(m1[r], tm1), mn2 = fmaxf(m2[r], tm2);
            float ts1 = 0.f, ts2 = 0.f;
            #pragma unroll
            for (int ct = 0; ct < 4; ++ct) {
                v1[ct] = __expf(v1[ct] - mn1);
                v2[ct] = __expf(v2[ct] - mn2);
                ts1 += v1[ct]; ts2 += v2[ct];
            }
            #pragma unroll
            for (int msk = 1; msk < 16; msk <<= 1) {
                ts1 += __shfl_xor(ts1, msk, 64);
                ts2 += __shfl_xor(ts2, msk, 64);
            }
            float sc1 = __expf(m1[r] - mn1), sc2 = __expf(m2[r] - mn2);
            l1[r] = l1[r] * sc1 + ts1;
            l2[r] = l2[r] * sc2 + ts2;
            m1[r] = mn1; m2[r] = mn2;
            #pragma unroll
            for (int d = 0; d < 8; ++d) { o1[d][r] *= sc1; o2[d][r] *= sc2; }
            // write P rows (swizzle chosen so the 4-row x 16-col write pattern is <=2-way)
            int pswz = ((rowl ^ (rowl >> 3)) & 7) << 4;
            #pragma unroll
            for (int ct = 0; ct < 4; ++ct) {
                int byte0 = (rowl * 128 + (ct * 16 + lr) * 2) ^ pswz;
                *(bf16*)((char*)Psm[0] + byte0) = __float2bfloat16(v1[ct]);
                *(bf16*)((char*)Psm[1] + byte0) = __float2bfloat16(v2[ct]);
            }
        }
        // in-wave cross-lane P handoff: drain LDS, then stop the scheduler hoisting MFMAs above it
        asm volatile("s_waitcnt lgkmcnt(0)" ::: "memory");
        __builtin_amdgcn_sched_barrier(0);

        // ---- PV for both P matrices
        int prow = w * 16 + lr;
        int pswz2 = ((prow ^ (prow >> 3)) & 7) << 4;
        bf16x8 p1f[2], p2f[2];
        #pragma unroll
        for (int s = 0; s < 2; ++s) {
            int pb = (prow * 128 + (s * 32 + lk * 8) * 2) ^ pswz2;
            p1f[s] = *(const bf16x8*)((const char*)Psm[0] + pb);
            p2f[s] = *(const bf16x8*)((const char*)Psm[1] + pb);
        }
        #pragma unroll
        for (int dt = 0; dt < 8; ++dt) {
            int d = dt * 16 + lr;
            int vswz = (d & 7) << 4;
            #pragma unroll
            for (int s = 0; s < 2; ++s) {
                bf16x8 vf = *(const bf16x8*)((const char*)Vsm + ((d * 128 + (s * 32 + lk * 8) * 2) ^ vswz));
                o1[dt] = __builtin_amdgcn_mfma_f32_16x16x32_bf16(p1f[s], vf, o1[dt], 0, 0, 0);
                o2[dt] = __builtin_amdgcn_mfma_f32_16x16x32_bf16(p2f[s], vf, o2[dt], 0, 0, 0);
            }
        }
    }

    // ---- epilogue: out = o1/l1 - LAMB * o2/l2
    #pragma unroll
    for (int r = 0; r < 4; ++r) {
        float inv1 = 1.0f / l1[r];
        float inv2 = LAMB / l2[r];
        bf16* dst = O + (size_t)(qb * 64 + w * 16 + lk * 4 + r) * DIMSZ + h * HDIM;
        #pragma unroll
        for (int dt = 0; dt < 8; ++dt)
            dst[dt * 16 + lr] = __float2bfloat16(o1[dt][r] * inv1 - o2[dt][r] * inv2);
    }
}

extern "C" void kernel_launch(void* const* d_in, const int* in_sizes, int n_in,
                              void* d_out, int out_size, void* d_ws, size_t ws_size,
                              hipStream_t stream)
{
    const float* x      = (const float*)d_in[0];
    const float* fcos   = (const float*)d_in[1];
    const float* fsin   = (const float*)d_in[2];
    const float* attn_w = (const float*)d_in[3];
    const float* wq     = (const float*)d_in[4];
    const float* wk     = (const float*)d_in[5];
    const float* wv     = (const float*)d_in[6];
    const float* wo     = (const float*)d_in[7];
    const float* ffn_w  = (const float*)d_in[8];
    const float* w1     = (const float*)d_in[9];
    const float* w2     = (const float*)d_in[10];
    const float* w3     = (const float*)d_in[11];
    float* out = (float*)d_out;
    char*  wsb = (char*)d_ws;

    // ws layout (bytes):
    //  phase A/B: h@0(8M) q@8M(16M) kb@24M(8M) vb@32M(8M)
    //  phase B/C: q_bf@0(8M) k_bf@8M(4M) vt@12M(4M) att@40M(8M)
    //  phase E:   u@0(46.1M) f@48M(8M) g@56M(22.1M) W@80M(23.1M)
    bf16*  h    = (bf16*) (wsb + 0);
    float* q    = (float*)(wsb + (size_t)( 8u << 20));
    float* kb   = (float*)(wsb + (size_t)(24u << 20));
    float* vb   = (float*)(wsb + (size_t)(32u << 20));
    bf16*  q_bf = (bf16*) (wsb + 0);
    bf16*  k_bf = (bf16*) (wsb + (size_t)( 8u << 20));
    bf16*  vt   = (bf16*) (wsb + (size_t)(12u << 20));
    bf16*  att  = (bf16*) (wsb + (size_t)(40u << 20));
    float* u    = (float*)(wsb + 0);
    bf16*  f    = (bf16*) (wsb + (size_t)(48u << 20));
    bf16*  g    = (bf16*) (wsb + (size_t)(56u << 20));
    bf16*  W    = (bf16*) (wsb + (size_t)(80u << 20));   // reused transposed-weight slot

    dim3 blk(256);

    rmsnorm_kernel<<<LSEQ, blk, 0, stream>>>(x, attn_w, h);

    tcast_kernel<<<dim3(64, 64), blk, 0, stream>>>(wq, W, 2048, 2048);
    gemm_bf16<0, float><<<dim3(16, 16), blk, 0, stream>>>(h, W, q, nullptr, 2048, 2048, 2048);
    tcast_kernel<<<dim3(32, 64), blk, 0, stream>>>(wk, W, 2048, 1024);
    gemm_bf16<0, float><<<dim3(8, 16), blk, 0, stream>>>(h, W, kb, nullptr, 2048, 1024, 2048);
    tcast_kernel<<<dim3(32, 64), blk, 0, stream>>>(wv, W, 2048, 1024);
    gemm_bf16<0, float><<<dim3(8, 16), blk, 0, stream>>>(h, W, vb, nullptr, 2048, 1024, 2048);

    // RoPE -> bf16 Q/K ; V -> transposed bf16 [d][key]
    rope_cast_kernel<<<(LSEQ * NHEADS * 64) / 256, blk, 0, stream>>>(q, fcos, fsin, q_bf, 4);
    rope_cast_kernel<<<(LSEQ * NKVH * 64) / 256, blk, 0, stream>>>(kb, fcos, fsin, k_bf, 3);
    tcast_kernel<<<dim3(32, 64), blk, 0, stream>>>(vb, vt, 2048, 1024);

    attn_mfma_kernel<<<dim3(LSEQ / 64, NHEADS), blk, 0, stream>>>(q_bf, k_bf, vt, att);

    tcast_kernel<<<dim3(64, 64), blk, 0, stream>>>(wo, W, 2048, 2048);
    gemm_bf16<1, float><<<dim3(16, 16), blk, 0, stream>>>(att, W, out, x, 2048, 2048, 2048);

    rmsnorm_kernel<<<LSEQ, blk, 0, stream>>>(out, ffn_w, f);

    tcast_kernel<<<dim3(176, 64), blk, 0, stream>>>(w1, W, 2048, 5632);
    gemm_bf16<0, float><<<dim3(44, 16), blk, 0, stream>>>(f, W, u, nullptr, 2048, 5632, 2048);
    tcast_kernel<<<dim3(176, 64), blk, 0, stream>>>(w3, W, 2048, 5632);
    gemm_bf16<2, bf16><<<dim3(44, 16), blk, 0, stream>>>(f, W, g, u, 2048, 5632, 2048);
    tcast_kernel<<<dim3(64, 176), blk, 0, stream>>>(w2, W, 5632, 2048);
    gemm_bf16<1, float><<<dim3(16, 16), blk, 0, stream>>>(g, W, out, out, 2048, 2048, 5632);
}

// Round 6
// 781.564 us; speedup vs baseline: 7.0416x; 1.2002x over previous
//
#include <hip/hip_runtime.h>
#include <hip/hip_bf16.h>

#define DIMSZ 2048
#define LSEQ 2048
#define NHEADS 16
#define NKVH 8
#define HDIM 128
#define HHALF 64
#define EPSV 1e-5f
#define LAMB 0.2f
#define SM_SCALE 0.125f

typedef __attribute__((ext_vector_type(8))) short bf16x8;
typedef __attribute__((ext_vector_type(4))) float f32x4;
typedef __hip_bfloat16 bf16;

__device__ __forceinline__ void gload_lds16(const void* g, void* l) {
    __builtin_amdgcn_global_load_lds((const __attribute__((address_space(1))) void*)g,
                                     (__attribute__((address_space(3))) void*)l, 16, 0, 0);
}

__device__ __forceinline__ float bf2f(short s) {
    unsigned u = ((unsigned)(unsigned short)s) << 16;
    return __builtin_bit_cast(float, u);
}

template<typename T> __device__ __forceinline__ T cvt_out(float v);
template<> __device__ __forceinline__ float cvt_out<float>(float v) { return v; }
template<> __device__ __forceinline__ bf16  cvt_out<bf16>(float v)  { return __float2bfloat16(v); }

// ---------------- RMSNorm: fp32 in, bf16 out ----------------
__global__ __launch_bounds__(256) void rmsnorm_kernel(const float* __restrict__ x,
                                                      const float* __restrict__ w,
                                                      bf16* __restrict__ out)
{
    int row = blockIdx.x;
    int t = threadIdx.x;
    const float* xr = x + (size_t)row * DIMSZ;
    float4 v0 = ((const float4*)xr)[t];
    float4 v1 = ((const float4*)xr)[t + 256];
    float s = v0.x*v0.x + v0.y*v0.y + v0.z*v0.z + v0.w*v0.w
            + v1.x*v1.x + v1.y*v1.y + v1.z*v1.z + v1.w*v1.w;
    #pragma unroll
    for (int m = 1; m < 64; m <<= 1) s += __shfl_xor(s, m, 64);
    __shared__ float red[4];
    int wid = t >> 6;
    if ((t & 63) == 0) red[wid] = s;
    __syncthreads();
    float tot = red[0] + red[1] + red[2] + red[3];
    float inv = rsqrtf(tot * (1.0f / DIMSZ) + EPSV);
    float4 w0 = ((const float4*)w)[t];
    float4 w1v = ((const float4*)w)[t + 256];
    bf16* orow = out + (size_t)row * DIMSZ;
    orow[t*4 + 0] = __float2bfloat16(v0.x*inv*w0.x);
    orow[t*4 + 1] = __float2bfloat16(v0.y*inv*w0.y);
    orow[t*4 + 2] = __float2bfloat16(v0.z*inv*w0.z);
    orow[t*4 + 3] = __float2bfloat16(v0.w*inv*w0.w);
    orow[1024 + t*4 + 0] = __float2bfloat16(v1.x*inv*w1v.x);
    orow[1024 + t*4 + 1] = __float2bfloat16(v1.y*inv*w1v.y);
    orow[1024 + t*4 + 2] = __float2bfloat16(v1.z*inv*w1v.z);
    orow[1024 + t*4 + 3] = __float2bfloat16(v1.w*inv*w1v.w);
}

// -------- transpose + cast: in fp32 [K][...] (row stride inStride) -> out bf16 [N][K] --------
__global__ __launch_bounds__(256) void tcast_kernel(const float* __restrict__ in,
                                                    bf16* __restrict__ out,
                                                    int K, int N, int inStride)
{
    __shared__ float tile[32][33];
    int bx = blockIdx.x, by = blockIdx.y;       // bx: N-tile, by: K-tile
    int tx = threadIdx.x & 31, tr = threadIdx.x >> 5;  // tr 0..7
    const float* src = in + (size_t)(by*32 + tr) * inStride + bx*32 + tx;
    #pragma unroll
    for (int r = 0; r < 32; r += 8)
        tile[tr + r][tx] = src[(size_t)r * inStride];
    __syncthreads();
    bf16* dst = out + (size_t)(bx*32 + tr) * K + by*32 + tx;
    #pragma unroll
    for (int r = 0; r < 32; r += 8)
        dst[(size_t)r * K] = __float2bfloat16(tile[tx][tr + r]);
}

// -------- RoPE + cast to bf16; src has row stride / col offset (float2 units) --------
__global__ __launch_bounds__(256) void rope_cast_kernel(const float* __restrict__ src,
                                                        int srcStrideF2, int srcOffF2,
                                                        const float* __restrict__ cosT,
                                                        const float* __restrict__ sinT,
                                                        bf16* __restrict__ out,
                                                        int log2nh)
{
    int idx = blockIdx.x * 256 + threadIdx.x;   // (l, head, j), j fastest
    int j = idx & 63;
    int l = idx >> (6 + log2nh);
    int rem = idx & ((64 << log2nh) - 1);
    float c = cosT[l * 64 + j];
    float s = sinT[l * 64 + j];
    float2 v = ((const float2*)src)[(size_t)l * srcStrideF2 + srcOffF2 + rem];
    __hip_bfloat162 rr;
    rr.x = __float2bfloat16(v.x * c - v.y * s);
    rr.y = __float2bfloat16(v.x * s + v.y * c);
    ((__hip_bfloat162*)out)[idx] = rr;
}

// ---------------- bf16 MFMA GEMM: C[M,N] = A[M,K] * BT[N,K]^T ----------------
// SPLIT: gridDim.z-way K-split, partial z written to C + z*M*N (fp32, no epilogue).
template<typename CT, bool SPLIT>
__global__ __launch_bounds__(256) void gemm_bf16(const bf16* __restrict__ A,
                                                 const bf16* __restrict__ BT,
                                                 CT* __restrict__ C,
                                                 int M, int N, int K)
{
    constexpr int BK = 32;
    __shared__ alignas(16) bf16 As[128 * BK];
    __shared__ alignas(16) bf16 Bs[128 * BK];
    int t = threadIdx.x;
    int lane = t & 63, wid = t >> 6;
    int wr = wid >> 1, wc = wid & 1;            // 2x2 wave grid, each wave 64x64
    int row0 = blockIdx.y * 128, col0 = blockIdx.x * 128;

    int kBeg = 0, kEnd = K;
    if (SPLIT) {
        int kh = K / (int)gridDim.z;
        kBeg = blockIdx.z * kh;
        kEnd = kBeg + kh;
        C += (size_t)blockIdx.z * M * N;
    }

    f32x4 acc[4][4];
    #pragma unroll
    for (int i = 0; i < 4; ++i)
        #pragma unroll
        for (int j = 0; j < 4; ++j)
            acc[i][j] = (f32x4){0.f, 0.f, 0.f, 0.f};

    for (int k0 = kBeg; k0 < kEnd; k0 += BK) {
        __syncthreads();                        // prev-iter LDS reads done
        #pragma unroll
        for (int s = 0; s < 2; ++s) {
            int c = s * 256 + t;                // chunk id
            int row = c >> 2, kc = c & 3;
            gload_lds16(A  + (size_t)(row0 + row) * K + k0 + kc * 8, (char*)As + c * 16);
            gload_lds16(BT + (size_t)(col0 + row) * K + k0 + kc * 8, (char*)Bs + c * 16);
        }
        __syncthreads();                        // drains vmcnt before compute

        bf16x8 a[4], b[4];
        int ch = lane >> 4;
        #pragma unroll
        for (int i = 0; i < 4; ++i) {
            int ra = wr * 64 + i * 16 + (lane & 15);
            int rb = wc * 64 + i * 16 + (lane & 15);
            a[i] = *(const bf16x8*)((const char*)As + ra * 64 + ch * 16);
            b[i] = *(const bf16x8*)((const char*)Bs + rb * 64 + ch * 16);
        }
        #pragma unroll
        for (int i = 0; i < 4; ++i)
            #pragma unroll
            for (int j = 0; j < 4; ++j)
                acc[i][j] = __builtin_amdgcn_mfma_f32_16x16x32_bf16(a[i], b[j], acc[i][j], 0, 0, 0);
    }

    int rl = lane >> 4;                          // D: row=(lane>>4)*4+reg, col=lane&15
    int cl = lane & 15;
    #pragma unroll
    for (int i = 0; i < 4; ++i) {
        #pragma unroll
        for (int j = 0; j < 4; ++j) {
            #pragma unroll
            for (int r = 0; r < 4; ++r) {
                int row = row0 + wr * 64 + i * 16 + rl * 4 + r;
                int col = col0 + wc * 64 + j * 16 + cl;
                C[(size_t)row * N + col] = cvt_out<CT>(acc[i][j][r]);
            }
        }
    }
}

// ---------------- combine: out = p0 + p1 + r (float4-vectorized) ----------------
__global__ __launch_bounds__(256) void combine_kernel(float* __restrict__ out,
                                                      const float* __restrict__ p0,
                                                      const float* __restrict__ p1,
                                                      const float* __restrict__ r)
{
    int i = blockIdx.x * 256 + threadIdx.x;
    float4 a = ((const float4*)p0)[i];
    float4 b = ((const float4*)p1)[i];
    float4 c = ((const float4*)r)[i];
    float4 o = {a.x + b.x + c.x, a.y + b.y + c.y, a.z + b.z + c.z, a.w + b.w + c.w};
    ((float4*)out)[i] = o;
}

// ---------------- silu-mul: g = silu(u13[:, :5632]) * u13[:, 5632:] ----------------
__global__ __launch_bounds__(256) void silu_mul_kernel(const bf16* __restrict__ u,
                                                       bf16* __restrict__ g)
{
    int idx = blockIdx.x * 256 + threadIdx.x;   // 2048*704 items of 8 bf16
    int row = idx / 704, c8 = (idx % 704) * 8;
    bf16x8 a = *(const bf16x8*)(u + (size_t)row * 11264 + c8);
    bf16x8 b = *(const bf16x8*)(u + (size_t)row * 11264 + 5632 + c8);
    alignas(16) bf16 o[8];
    #pragma unroll
    for (int j = 0; j < 8; ++j) {
        float fa = bf2f(a[j]), fb = bf2f(b[j]);
        o[j] = __float2bfloat16((fa / (1.0f + __expf(-fa))) * fb);
    }
    *(bf16x8*)(g + (size_t)row * 5632 + c8) = *(bf16x8*)o;
}

// ---------------- Differential GQA flash attention, bf16 MFMA ----------------
// Qb [L][NH*128] bf16 ; Kb [L][NKV*128] bf16 ; Vt [NKV*128][L] bf16
// grid (L/64, NH) reversed qb; block 256 = 4 waves, each wave owns 16 q-rows.
__global__ __launch_bounds__(256) void attn_mfma_kernel(const bf16* __restrict__ Qb,
                                                        const bf16* __restrict__ Kb,
                                                        const bf16* __restrict__ Vt,
                                                        bf16* __restrict__ O)
{
    int qb = (int)gridDim.x - 1 - (int)blockIdx.x;   // heavy blocks first
    int h = blockIdx.y;
    int kvh = h >> 1;
    int t = threadIdx.x;
    int lane = t & 63, w = t >> 6;
    int lr = lane & 15;          // A-row / B-col selector
    int lk = lane >> 4;          // k-chunk selector (0..3)

    __shared__ alignas(16) bf16 Ksm[64 * 128];
    __shared__ alignas(16) bf16 Vsm[128 * 64];
    __shared__ alignas(16) bf16 Psm[2][64 * 64];

    bf16x8 qf[4];
    {
        const char* qrow = (const char*)Qb + ((size_t)(qb * 64 + w * 16 + lr) * (NHEADS * HDIM) + h * HDIM) * 2;
        #pragma unroll
        for (int s = 0; s < 4; ++s)
            qf[s] = *(const bf16x8*)(qrow + (s * 32 + lk * 8) * 2);
    }

    f32x4 o1[8], o2[8];
    #pragma unroll
    for (int d = 0; d < 8; ++d) { o1[d] = (f32x4){0.f,0.f,0.f,0.f}; o2[d] = (f32x4){0.f,0.f,0.f,0.f}; }
    float m1[4], l1[4], m2[4], l2[4];
    #pragma unroll
    for (int r = 0; r < 4; ++r) { m1[r] = -1e30f; m2[r] = -1e30f; l1[r] = 0.f; l2[r] = 0.f; }

    int nt = qb + 1;
    for (int it = 0; it < nt; ++it) {
        int k0 = it * 64;
        bf16x8 kreg[4], vreg[4];
        #pragma unroll
        for (int c4 = 0; c4 < 4; ++c4) {
            int c = c4 * 256 + t;
            int key = c >> 4, db = (c & 15) * 16;
            kreg[c4] = *(const bf16x8*)((const char*)Kb
                        + (size_t)(k0 + key) * (NKVH * HDIM * 2) + kvh * HDIM * 2 + db);
            int d = c >> 3, kbyte = (c & 7) * 16;
            vreg[c4] = *(const bf16x8*)((const char*)Vt
                        + ((size_t)(kvh * HDIM + d) * LSEQ + k0) * 2 + kbyte);
        }
        __syncthreads();
        #pragma unroll
        for (int c4 = 0; c4 < 4; ++c4) {
            int c = c4 * 256 + t;
            int key = c >> 4, db = (c & 15) * 16;
            *(bf16x8*)((char*)Ksm + ((key * 256 + db) ^ ((key & 7) << 4))) = kreg[c4];
            int d = c >> 3, kbyte = (c & 7) * 16;
            *(bf16x8*)((char*)Vsm + ((d * 128 + kbyte) ^ ((d & 7) << 4))) = vreg[c4];
        }
        __syncthreads();

        f32x4 s1a[4], s2a[4];
        #pragma unroll
        for (int ct = 0; ct < 4; ++ct) { s1a[ct] = (f32x4){0.f,0.f,0.f,0.f}; s2a[ct] = (f32x4){0.f,0.f,0.f,0.f}; }
        #pragma unroll
        for (int ct = 0; ct < 4; ++ct) {
            int key = ct * 16 + lr;
            int kswz = (key & 7) << 4;
            #pragma unroll
            for (int s = 0; s < 2; ++s) {
                bf16x8 kb1 = *(const bf16x8*)((const char*)Ksm + ((key * 256 + (s * 32 + lk * 8) * 2) ^ kswz));
                bf16x8 kb2 = *(const bf16x8*)((const char*)Ksm + ((key * 256 + (64 + s * 32 + lk * 8) * 2) ^ kswz));
                s1a[ct] = __builtin_amdgcn_mfma_f32_16x16x32_bf16(qf[s],     kb1, s1a[ct], 0, 0, 0);
                s2a[ct] = __builtin_amdgcn_mfma_f32_16x16x32_bf16(qf[2 + s], kb2, s2a[ct], 0, 0, 0);
            }
        }

        bool diag = (it == nt - 1);
        #pragma unroll
        for (int r = 0; r < 4; ++r) {
            int rowl = w * 16 + lk * 4 + r;
            int rg = qb * 64 + rowl;
            float v1[4], v2[4];
            #pragma unroll
            for (int ct = 0; ct < 4; ++ct) {
                v1[ct] = s1a[ct][r] * SM_SCALE;
                v2[ct] = s2a[ct][r] * SM_SCALE;
                if (diag) {
                    int cg = k0 + ct * 16 + lr;
                    if (cg > rg) { v1[ct] = -1e30f; v2[ct] = -1e30f; }
                }
            }
            float tm1 = fmaxf(fmaxf(v1[0], v1[1]), fmaxf(v1[2], v1[3]));
            float tm2 = fmaxf(fmaxf(v2[0], v2[1]), fmaxf(v2[2], v2[3]));
            #pragma unroll
            for (int msk = 1; msk < 16; msk <<= 1) {
                tm1 = fmaxf(tm1, __shfl_xor(tm1, msk, 64));
                tm2 = fmaxf(tm2, __shfl_xor(tm2, msk, 64));
            }
            float mn1 = fmaxf(m1[r], tm1), mn2 = fmaxf(m2[r], tm2);
            float ts1 = 0.f, ts2 = 0.f;
            #pragma unroll
            for (int ct = 0; ct < 4; ++ct) {
                v1[ct] = __expf(v1[ct] - mn1);
                v2[ct] = __expf(v2[ct] - mn2);
                ts1 += v1[ct]; ts2 += v2[ct];
            }
            #pragma unroll
            for (int msk = 1; msk < 16; msk <<= 1) {
                ts1 += __shfl_xor(ts1, msk, 64);
                ts2 += __shfl_xor(ts2, msk, 64);
            }
            float sc1 = __expf(m1[r] - mn1), sc2 = __expf(m2[r] - mn2);
            l1[r] = l1[r] * sc1 + ts1;
            l2[r] = l2[r] * sc2 + ts2;
            m1[r] = mn1; m2[r] = mn2;
            #pragma unroll
            for (int d = 0; d < 8; ++d) { o1[d][r] *= sc1; o2[d][r] *= sc2; }
            int pswz = ((rowl ^ (rowl >> 3)) & 7) << 4;
            #pragma unroll
            for (int ct = 0; ct < 4; ++ct) {
                int byte0 = (rowl * 128 + (ct * 16 + lr) * 2) ^ pswz;
                *(bf16*)((char*)Psm[0] + byte0) = __float2bfloat16(v1[ct]);
                *(bf16*)((char*)Psm[1] + byte0) = __float2bfloat16(v2[ct]);
            }
        }
        asm volatile("s_waitcnt lgkmcnt(0)" ::: "memory");
        __builtin_amdgcn_sched_barrier(0);

        int prow = w * 16 + lr;
        int pswz2 = ((prow ^ (prow >> 3)) & 7) << 4;
        bf16x8 p1f[2], p2f[2];
        #pragma unroll
        for (int s = 0; s < 2; ++s) {
            int pb = (prow * 128 + (s * 32 + lk * 8) * 2) ^ pswz2;
            p1f[s] = *(const bf16x8*)((const char*)Psm[0] + pb);
            p2f[s] = *(const bf16x8*)((const char*)Psm[1] + pb);
        }
        #pragma unroll
        for (int dt = 0; dt < 8; ++dt) {
            int d = dt * 16 + lr;
            int vswz = (d & 7) << 4;
            #pragma unroll
            for (int s = 0; s < 2; ++s) {
                bf16x8 vf = *(const bf16x8*)((const char*)Vsm + ((d * 128 + (s * 32 + lk * 8) * 2) ^ vswz));
                o1[dt] = __builtin_amdgcn_mfma_f32_16x16x32_bf16(p1f[s], vf, o1[dt], 0, 0, 0);
                o2[dt] = __builtin_amdgcn_mfma_f32_16x16x32_bf16(p2f[s], vf, o2[dt], 0, 0, 0);
            }
        }
    }

    #pragma unroll
    for (int r = 0; r < 4; ++r) {
        float inv1 = 1.0f / l1[r];
        float inv2 = LAMB / l2[r];
        bf16* dst = O + (size_t)(qb * 64 + w * 16 + lk * 4 + r) * DIMSZ + h * HDIM;
        #pragma unroll
        for (int dt = 0; dt < 8; ++dt)
            dst[dt * 16 + lr] = __float2bfloat16(o1[dt][r] * inv1 - o2[dt][r] * inv2);
    }
}

extern "C" void kernel_launch(void* const* d_in, const int* in_sizes, int n_in,
                              void* d_out, int out_size, void* d_ws, size_t ws_size,
                              hipStream_t stream)
{
    const float* x      = (const float*)d_in[0];
    const float* fcos   = (const float*)d_in[1];
    const float* fsin   = (const float*)d_in[2];
    const float* attn_w = (const float*)d_in[3];
    const float* wq     = (const float*)d_in[4];
    const float* wk     = (const float*)d_in[5];
    const float* wv     = (const float*)d_in[6];
    const float* wo     = (const float*)d_in[7];
    const float* ffn_w  = (const float*)d_in[8];
    const float* w1     = (const float*)d_in[9];
    const float* w2     = (const float*)d_in[10];
    const float* w3     = (const float*)d_in[11];
    float* out = (float*)d_out;
    char*  wsb = (char*)d_ws;

    // ws layout (MiB offsets), peak 96 MiB:
    //  h@0(8) W4@16(16) qkv@40(32) q_bf@80(8) k_bf@88(4) vt@92(4)
    //  att@0(8) WoT@16(8) Pw@40(32) f@0(8, after att dead) Wbig@8(44)
    //  u13@52(44) g@8(22) W2T@30(22) P2@52(32)
    bf16*  h    = (bf16*) (wsb + 0);
    bf16*  W4   = (bf16*) (wsb + (size_t)(16u << 20));
    float* qkv  = (float*)(wsb + (size_t)(40u << 20));
    bf16*  q_bf = (bf16*) (wsb + (size_t)(80u << 20));
    bf16*  k_bf = (bf16*) (wsb + (size_t)(88u << 20));
    bf16*  vt   = (bf16*) (wsb + (size_t)(92u << 20));
    bf16*  att  = (bf16*) (wsb + 0);
    bf16*  WoT  = (bf16*) (wsb + (size_t)(16u << 20));
    float* Pw   = (float*)(wsb + (size_t)(40u << 20));
    bf16*  f    = (bf16*) (wsb + 0);
    bf16*  Wbig = (bf16*) (wsb + (size_t)( 8u << 20));
    bf16*  u13  = (bf16*) (wsb + (size_t)(52u << 20));
    bf16*  g    = (bf16*) (wsb + (size_t)( 8u << 20));
    bf16*  W2T  = (bf16*) (wsb + (size_t)(30u << 20));
    float* P2   = (float*)(wsb + (size_t)(52u << 20));

    const size_t PSZ = (size_t)2048 * 2048;      // partial size (floats)
    dim3 blk(256);

    // ---- attention input path
    rmsnorm_kernel<<<LSEQ, blk, 0, stream>>>(x, attn_w, h);
    tcast_kernel<<<dim3(64, 64), blk, 0, stream>>>(wq, W4,                 2048, 2048, 2048);
    tcast_kernel<<<dim3(32, 64), blk, 0, stream>>>(wk, W4 + 2048*2048,     2048, 1024, 1024);
    tcast_kernel<<<dim3(32, 64), blk, 0, stream>>>(wv, W4 + 3072*2048,     2048, 1024, 1024);
    gemm_bf16<float, false><<<dim3(32, 16), blk, 0, stream>>>(h, W4, qkv, 2048, 4096, 2048);

    rope_cast_kernel<<<8192, blk, 0, stream>>>(qkv, 2048,    0, fcos, fsin, q_bf, 4);
    rope_cast_kernel<<<4096, blk, 0, stream>>>(qkv, 2048, 1024, fcos, fsin, k_bf, 3);
    tcast_kernel<<<dim3(32, 64), blk, 0, stream>>>(qkv + 3072, vt, 2048, 1024, 4096);

    attn_mfma_kernel<<<dim3(LSEQ / 64, NHEADS), blk, 0, stream>>>(q_bf, k_bf, vt, att);

    // ---- Wo (split-K=2) + residual combine: out = x + att@Wo
    tcast_kernel<<<dim3(64, 64), blk, 0, stream>>>(wo, WoT, 2048, 2048, 2048);
    gemm_bf16<float, true><<<dim3(16, 16, 2), blk, 0, stream>>>(att, WoT, Pw, 2048, 2048, 2048);
    combine_kernel<<<4096, blk, 0, stream>>>(out, Pw, Pw + PSZ, x);

    // ---- FFN
    rmsnorm_kernel<<<LSEQ, blk, 0, stream>>>(out, ffn_w, f);
    tcast_kernel<<<dim3(176, 64), blk, 0, stream>>>(w1, Wbig,             2048, 5632, 5632);
    tcast_kernel<<<dim3(176, 64), blk, 0, stream>>>(w3, Wbig + 5632*2048, 2048, 5632, 5632);
    gemm_bf16<bf16, false><<<dim3(88, 16), blk, 0, stream>>>(f, Wbig, u13, 2048, 11264, 2048);
    silu_mul_kernel<<<5632, blk, 0, stream>>>(u13, g);

    tcast_kernel<<<dim3(64, 176), blk, 0, stream>>>(w2, W2T, 5632, 2048, 2048);
    gemm_bf16<float, true><<<dim3(16, 16, 2), blk, 0, stream>>>(g, W2T, P2, 2048, 2048, 5632);
    combine_kernel<<<4096, blk, 0, stream>>>(out, P2, P2 + PSZ, out);
}